// Round 11
// baseline (1430.554 us; speedup 1.0000x reference)
//
#include <hip/hip_runtime.h>
#include <hip/hip_fp16.h>

// ---------------------------------------------------------------------------
// 2-layer GCN: out = GCNConv2( relu(GCNConv1(x)) )
// GCNConv(x,W,b): h = x@W ; out[d] = dinv[d]*( sum_{s->d} h[s]*dinv[s] + h[d]*dinv[d] ) + b
// dinv = rsqrt(in-degree + 1) (self-loops).
//
// Build = counting sort with exact bases (zero global atomics):
//  A1 hist_gemm: per-block LDS hist over 128-node buckets -> H[bucket][block];
//     payload pk=(dlocal<<17|src), meta=(rank<<10|bucket) to sequential tmp.
//     gemm1 (x@W1 -> f16, MFMA) fused in.
//  A2 scan_hist: exact (bucket,block) bases + bucket totals T.
//  A3 place: tmp -> exactly-packed per-bucket arena. No atomics.
//  count_dinv: per-bucket LDS histogram -> dinv only.
// Aggregation reads the arena DIRECTLY (no per-node CSR at all):
//  agg_lds: block per bucket, f32 accumulators acc[128][65] in LDS,
//  edge-parallel gather (zero predication waste) + ds_add_f32.
// ---------------------------------------------------------------------------

#define CAPB  3072    // arena slots per 128-node bucket (mean ~2046)
#define BKMAX 1024

typedef _Float16 f16x8 __attribute__((ext_vector_type(8)));
typedef float f32x4 __attribute__((ext_vector_type(4)));

struct alignas(8) H4 { __half2 a, b; };
__device__ inline H4 pack4(float x, float y, float z, float w) {
  H4 r; r.a = __floats2half2_rn(x, y); r.b = __floats2half2_rn(z, w); return r;
}

// Detect whether edge_index was stored as int64 (all high words of values <N
// are zero) or int32 (odd words are random node ids, nonzero w.h.p.).
__global__ void detect_i64_kernel(const unsigned int* __restrict__ w, int ncheck,
                                  int* __restrict__ flag) {
  __shared__ int nz;
  if (threadIdx.x == 0) nz = 0;
  __syncthreads();
  for (int i = threadIdx.x; i < ncheck; i += blockDim.x) {
    if (w[2 * i + 1] != 0u) nz = 1;
  }
  __syncthreads();
  if (threadIdx.x == 0) flag[0] = (nz == 0) ? 1 : 0;
}

// A1 fused with GEMM1. Blocks [0,SB): 2048 edges each -> LDS hist, tmp
// streams, H row. Blocks [SB, SB+G1): g = x @ W1 (unscaled f16, MFMA).
__global__ __launch_bounds__(256) void hist_gemm_kernel(
    const int* __restrict__ edges, int E, const int* __restrict__ flag,
    int* __restrict__ Hh, int SB, int nbk,
    int* __restrict__ tmp_pk, int* __restrict__ tmp_mt,
    const float* __restrict__ A, const float* __restrict__ W,
    __half* __restrict__ g, int n) {
  __shared__ __align__(16) char smem[34816];  // union: {Af,Wf} | hist
  const int t = threadIdx.x;
  const int bid = (int)blockIdx.x;

  if (bid < SB) {
    int* hist = (int*)smem;  // [BKMAX]
    const int f = flag[0];
    const int blk0 = bid * 2048;

    for (int i = t; i < nbk; i += 256) hist[i] = 0;
    __syncthreads();

    if (blk0 + 2048 <= E) {  // full block: 8 edges/thread, vector loads
      int sv[8], dv[8];
      if (f) {  // int64 storage: value in low word of each qword
#pragma unroll
        for (int u = 0; u < 4; ++u) {
          const int eg = blk0 + (u * 256 + t) * 2;  // pair of edges
          const int4 a = *(const int4*)&edges[2 * (size_t)eg];
          const int4 b = *(const int4*)&edges[2 * ((size_t)E + eg)];
          sv[u * 2] = a.x; sv[u * 2 + 1] = a.z;
          dv[u * 2] = b.x; dv[u * 2 + 1] = b.z;
        }
      } else {
#pragma unroll
        for (int u = 0; u < 2; ++u) {
          const int eg = blk0 + (u * 256 + t) * 4;
          const int4 a = *(const int4*)&edges[eg];
          const int4 b = *(const int4*)&edges[(size_t)E + eg];
          sv[u * 4] = a.x; sv[u * 4 + 1] = a.y; sv[u * 4 + 2] = a.z; sv[u * 4 + 3] = a.w;
          dv[u * 4] = b.x; dv[u * 4 + 1] = b.y; dv[u * 4 + 2] = b.z; dv[u * 4 + 3] = b.w;
        }
      }
      int pk[8], mt[8];
#pragma unroll
      for (int i = 0; i < 8; ++i) {
        const int bk = dv[i] >> 7;
        const int rk = atomicAdd(&hist[bk], 1);
        pk[i] = ((dv[i] & 127) << 17) | sv[i];
        mt[i] = bk | (rk << 10);
      }
      if (f) {
#pragma unroll
        for (int u = 0; u < 4; ++u) {
          const int eg = blk0 + (u * 256 + t) * 2;
          *(int2*)&tmp_pk[eg] = make_int2(pk[u * 2], pk[u * 2 + 1]);
          *(int2*)&tmp_mt[eg] = make_int2(mt[u * 2], mt[u * 2 + 1]);
        }
      } else {
        *(int4*)&tmp_pk[blk0 + t * 4]        = make_int4(pk[0], pk[1], pk[2], pk[3]);
        *(int4*)&tmp_pk[blk0 + 1024 + t * 4] = make_int4(pk[4], pk[5], pk[6], pk[7]);
        *(int4*)&tmp_mt[blk0 + t * 4]        = make_int4(mt[0], mt[1], mt[2], mt[3]);
        *(int4*)&tmp_mt[blk0 + 1024 + t * 4] = make_int4(mt[4], mt[5], mt[6], mt[7]);
      }
    } else {  // tail block
      for (int e = blk0 + t; e < E; e += 256) {
        const int s = f ? edges[2 * (size_t)e] : edges[e];
        const int d = f ? edges[2 * ((size_t)E + e)] : edges[(size_t)E + e];
        const int bk = d >> 7;
        const int rk = atomicAdd(&hist[bk], 1);
        tmp_pk[e] = ((d & 127) << 17) | s;
        tmp_mt[e] = bk | (rk << 10);
      }
    }
    __syncthreads();
    for (int i = t; i < nbk; i += 256) Hh[(size_t)i * SB + bid] = hist[i];
    return;
  }

  // ---------------- GEMM1 path (MFMA f16, K=128) ----------------
  _Float16 (*Af)[136] = (_Float16(*)[136])smem;            // A[row][k], +8 pad
  _Float16 (*Wf)[136] = (_Float16(*)[136])(smem + 17408);  // Wt[col][k]
  const int row0 = (bid - SB) * 64;

  {  // stage A tile (64x128 f32 -> f16), coalesced
    const int r = t >> 2, k0 = (t & 3) << 5;
    const int gr = row0 + r;
    if (gr < n) {
#pragma unroll
      for (int q = 0; q < 4; ++q) {
        float4 a = *(const float4*)&A[(size_t)gr * 128 + k0 + q * 8];
        float4 b = *(const float4*)&A[(size_t)gr * 128 + k0 + q * 8 + 4];
        f16x8 v;
        v[0] = (_Float16)a.x; v[1] = (_Float16)a.y; v[2] = (_Float16)a.z; v[3] = (_Float16)a.w;
        v[4] = (_Float16)b.x; v[5] = (_Float16)b.y; v[6] = (_Float16)b.z; v[7] = (_Float16)b.w;
        *(f16x8*)&Af[r][k0 + q * 8] = v;
      }
    } else {
      f16x8 z = {0, 0, 0, 0, 0, 0, 0, 0};
#pragma unroll
      for (int q = 0; q < 4; ++q) *(f16x8*)&Af[r][k0 + q * 8] = z;
    }
  }
  {  // stage W transposed (Wt[col][k]), coalesced per k-row
    const int c = t & 63, kq = t >> 6;
#pragma unroll
    for (int i = 0; i < 32; ++i)
      Wf[c][kq * 32 + i] = (_Float16)W[(size_t)(kq * 32 + i) * 64 + c];
  }
  __syncthreads();

  const int wid = t >> 6, lane = t & 63;
  const int lr = lane & 15, kg = lane >> 4;
  f32x4 acc[4] = {{0, 0, 0, 0}, {0, 0, 0, 0}, {0, 0, 0, 0}, {0, 0, 0, 0}};
#pragma unroll
  for (int kc = 0; kc < 4; ++kc) {
    f16x8 av = *(const f16x8*)&Af[wid * 16 + lr][kc * 32 + kg * 8];
#pragma unroll
    for (int ct = 0; ct < 4; ++ct) {
      f16x8 bv = *(const f16x8*)&Wf[ct * 16 + lr][kc * 32 + kg * 8];
      acc[ct] = __builtin_amdgcn_mfma_f32_16x16x32_f16(av, bv, acc[ct], 0, 0, 0);
    }
  }
#pragma unroll
  for (int ct = 0; ct < 4; ++ct) {
#pragma unroll
    for (int rg = 0; rg < 4; ++rg) {
      const int r = row0 + wid * 16 + kg * 4 + rg;
      if (r < n) g[(size_t)r * 64 + ct * 16 + lr] = (__half)(float)acc[ct][rg];
    }
  }
}

// A2: per-bucket exclusive scan of H row (SB entries) + bucket total T.
__global__ __launch_bounds__(256) void scan_hist_kernel(
    int* __restrict__ Hh, int SB, int* __restrict__ T) {
  __shared__ int sm[256];
  __shared__ int carry;
  const int b = blockIdx.x;
  const int t = threadIdx.x;
  if (t == 0) carry = 0;
  __syncthreads();
  int* __restrict__ row = Hh + (size_t)b * SB;
  for (int base = 0; base < SB; base += 256) {
    const int i = base + t;
    const int v = (i < SB) ? row[i] : 0;
    sm[t] = v;
    __syncthreads();
    for (int off = 1; off < 256; off <<= 1) {
      int u = (t >= off) ? sm[t - off] : 0;
      __syncthreads();
      sm[t] += u;
      __syncthreads();
    }
    const int excl = sm[t] - v + carry;
    if (i < SB) row[i] = excl;
    __syncthreads();
    if (t == 0) carry += sm[255];
    __syncthreads();
  }
  if (t == 0) T[b] = carry;
}

// A3: stream tmp, place each edge at its exact arena slot. No atomics.
__global__ __launch_bounds__(256) void place_kernel(
    const int* __restrict__ tmp_pk, const int* __restrict__ tmp_mt,
    const int* __restrict__ Hh, int SB, int E, int* __restrict__ arena) {
  const int e0 = ((int)blockIdx.x * 256 + (int)threadIdx.x) * 4;
  if (e0 >= E) return;
  const int blk = e0 >> 11;  // originating A1 block (2048-edge chunks)
  if (e0 + 4 <= E) {
    const int4 pk = *(const int4*)&tmp_pk[e0];
    const int4 mt = *(const int4*)&tmp_mt[e0];
    const int b0 = mt.x & 1023, b1 = mt.y & 1023, b2 = mt.z & 1023, b3 = mt.w & 1023;
    const int p0 = Hh[(size_t)b0 * SB + blk] + (mt.x >> 10);
    const int p1 = Hh[(size_t)b1 * SB + blk] + (mt.y >> 10);
    const int p2 = Hh[(size_t)b2 * SB + blk] + (mt.z >> 10);
    const int p3 = Hh[(size_t)b3 * SB + blk] + (mt.w >> 10);
    if (p0 < CAPB) arena[(size_t)b0 * CAPB + p0] = pk.x;
    if (p1 < CAPB) arena[(size_t)b1 * CAPB + p1] = pk.y;
    if (p2 < CAPB) arena[(size_t)b2 * CAPB + p2] = pk.z;
    if (p3 < CAPB) arena[(size_t)b3 * CAPB + p3] = pk.w;
  } else {
    for (int e = e0; e < E; ++e) {
      const int mt = tmp_mt[e];
      const int bk = mt & 1023;
      const int p = Hh[(size_t)bk * SB + blk] + (mt >> 10);
      if (p < CAPB) arena[(size_t)bk * CAPB + p] = tmp_pk[e];
    }
  }
}

// Per-bucket degree histogram -> dinv (no CSR needed downstream).
__global__ __launch_bounds__(256) void count_dinv_kernel(
    const int* __restrict__ T, const int* __restrict__ arena,
    int n, float* __restrict__ dinv) {
  __shared__ int lc[128];
  const int b = blockIdx.x;
  const int t = threadIdx.x;
  if (t < 128) lc[t] = 0;
  __syncthreads();
  int cnt = T[b];
  if (cnt > CAPB) cnt = CAPB;
  const int* __restrict__ seg = &arena[(size_t)b * CAPB];
  for (int j = t; j < cnt; j += 256) atomicAdd(&lc[seg[j] >> 17], 1);
  __syncthreads();
  const int d = (b << 7) + t;
  if (t < 128 && d < n) dinv[d] = rsqrtf((float)(lc[t] + 1));
}

// Arena-direct aggregation: one block per 128-node bucket; f32 accumulators
// in LDS (stride 65 to spread banks). Edge-parallel: 32 edge slots x 16
// channel-lanes, unroll 4 -> 4 independent 128B gathers in flight per thread,
// zero predication waste. ds_add_f32 accumulate; epilogue applies dinv[d],
// bias, optional relu.
template <bool EDGE_SCALE, bool RELU, typename OUT>
__global__ __launch_bounds__(512) void agg_lds_kernel(
    const __half* __restrict__ hs, const int* __restrict__ T,
    const int* __restrict__ arena, const float* __restrict__ dinv,
    const float* __restrict__ bias, OUT* __restrict__ out, int n) {
  __shared__ float acc[128][65];  // 33.3 KB
  const int b = blockIdx.x;
  const int t = threadIdx.x;
  const int node0 = b << 7;

  {  // init with self-loop term (weight dinv[d] for layer1, 1 for layer2)
    const int r = t >> 2;          // 0..127
    const int cg = (t & 3) << 4;   // 0,16,32,48
    const int d = node0 + r;
    if (d < n) {
      const float wself = EDGE_SCALE ? dinv[d] : 1.f;
#pragma unroll
      for (int q = 0; q < 4; ++q) {
        H4 v = *(const H4*)&hs[(size_t)d * 64 + cg + q * 4];
        float2 f = __half22float2(v.a), g = __half22float2(v.b);
        acc[r][cg + q * 4 + 0] = wself * f.x;
        acc[r][cg + q * 4 + 1] = wself * f.y;
        acc[r][cg + q * 4 + 2] = wself * g.x;
        acc[r][cg + q * 4 + 3] = wself * g.y;
      }
    } else {
#pragma unroll
      for (int c = 0; c < 16; ++c) acc[r][cg + c] = 0.f;
    }
  }
  __syncthreads();

  int cnt = T[b];
  if (cnt > CAPB) cnt = CAPB;
  const int* __restrict__ seg = &arena[(size_t)b * CAPB];
  const int eq = t >> 4;         // edge slot 0..31
  const int gl = (t & 15) << 2;  // channel base 0,4,..,60

  for (int j = eq; j < cnt; j += 128) {
    int p[4];
    bool pr[4];
#pragma unroll
    for (int u = 0; u < 4; ++u) {
      const int jj = j + u * 32;
      pr[u] = jj < cnt;
      p[u] = pr[u] ? seg[jj] : 0;
    }
    H4 v[4];
    float w[4];
#pragma unroll
    for (int u = 0; u < 4; ++u) {
      const int s = p[u] & 131071;
      v[u] = *(const H4*)&hs[(size_t)s * 64 + gl];
      w[u] = pr[u] ? (EDGE_SCALE ? dinv[s] : 1.f) : 0.f;
    }
#pragma unroll
    for (int u = 0; u < 4; ++u) {
      if (pr[u]) {
        const int dl = p[u] >> 17;
        float2 f = __half22float2(v[u].a), g = __half22float2(v[u].b);
        atomicAdd(&acc[dl][gl + 0], w[u] * f.x);
        atomicAdd(&acc[dl][gl + 1], w[u] * f.y);
        atomicAdd(&acc[dl][gl + 2], w[u] * g.x);
        atomicAdd(&acc[dl][gl + 3], w[u] * g.y);
      }
    }
  }
  __syncthreads();

  {  // epilogue
    const int r = t >> 2, cg = (t & 3) << 4;
    const int d = node0 + r;
    if (d >= n) return;
    const float dd = dinv[d];
    float o[16];
#pragma unroll
    for (int c = 0; c < 16; ++c) {
      float val = fmaf(acc[r][cg + c], dd, bias[cg + c]);
      if (RELU) val = fmaxf(val, 0.f);
      o[c] = val;
    }
    if constexpr (sizeof(OUT) == 2) {
#pragma unroll
      for (int q = 0; q < 4; ++q)
        *(H4*)&out[(size_t)d * 64 + cg + q * 4] =
            pack4(o[q * 4], o[q * 4 + 1], o[q * 4 + 2], o[q * 4 + 3]);
    } else {
#pragma unroll
      for (int q = 0; q < 4; ++q)
        *(float4*)&out[(size_t)d * 64 + cg + q * 4] =
            make_float4(o[q * 4], o[q * 4 + 1], o[q * 4 + 2], o[q * 4 + 3]);
    }
  }
}

// GEMM2 (MFMA f16, K=64): hs2 = (h @ W2) * dinv[row], f16 in (h), f16 out.
__global__ __launch_bounds__(256) void gemm2_kernel(
    const _Float16* __restrict__ h, const float* __restrict__ W,
    const float* __restrict__ dinv, __half* __restrict__ out, int n) {
  __shared__ __align__(16) _Float16 Af[64][72];  // h[row][k], +8 pad
  __shared__ __align__(16) _Float16 Wf[64][72];  // Wt[col][k]
  const int t = threadIdx.x;
  const int row0 = blockIdx.x * 64;

  {  // stage h tile (f16 direct copy)
    const int r = t >> 2, k0 = (t & 3) << 4;
    const int gr = row0 + r;
    if (gr < n) {
      *(f16x8*)&Af[r][k0] = *(const f16x8*)&h[(size_t)gr * 64 + k0];
      *(f16x8*)&Af[r][k0 + 8] = *(const f16x8*)&h[(size_t)gr * 64 + k0 + 8];
    } else {
      f16x8 z = {0, 0, 0, 0, 0, 0, 0, 0};
      *(f16x8*)&Af[r][k0] = z;
      *(f16x8*)&Af[r][k0 + 8] = z;
    }
  }
  {  // stage W2 transposed
    const int c = t & 63, kq = t >> 6;
#pragma unroll
    for (int i = 0; i < 16; ++i)
      Wf[c][kq * 16 + i] = (_Float16)W[(size_t)(kq * 16 + i) * 64 + c];
  }
  __syncthreads();

  const int wid = t >> 6, lane = t & 63;
  const int lr = lane & 15, kg = lane >> 4;
  f32x4 acc[4] = {{0, 0, 0, 0}, {0, 0, 0, 0}, {0, 0, 0, 0}, {0, 0, 0, 0}};
#pragma unroll
  for (int kc = 0; kc < 2; ++kc) {
    f16x8 av = *(const f16x8*)&Af[wid * 16 + lr][kc * 32 + kg * 8];
#pragma unroll
    for (int ct = 0; ct < 4; ++ct) {
      f16x8 bv = *(const f16x8*)&Wf[ct * 16 + lr][kc * 32 + kg * 8];
      acc[ct] = __builtin_amdgcn_mfma_f32_16x16x32_f16(av, bv, acc[ct], 0, 0, 0);
    }
  }
  float sc[4];
#pragma unroll
  for (int rg = 0; rg < 4; ++rg) {
    const int r = row0 + wid * 16 + kg * 4 + rg;
    sc[rg] = (r < n) ? dinv[r] : 0.f;
  }
#pragma unroll
  for (int ct = 0; ct < 4; ++ct) {
#pragma unroll
    for (int rg = 0; rg < 4; ++rg) {
      const int r = row0 + wid * 16 + kg * 4 + rg;
      if (r < n) out[(size_t)r * 64 + ct * 16 + lr] = (__half)((float)acc[ct][rg] * sc[rg]);
    }
  }
}

extern "C" void kernel_launch(void* const* d_in, const int* in_sizes, int n_in,
                              void* d_out, int out_size, void* d_ws, size_t ws_size,
                              hipStream_t stream) {
  const float* x  = (const float*)d_in[0];
  const int*   ei = (const int*)d_in[1];
  const float* W1 = (const float*)d_in[2];
  const float* b1 = (const float*)d_in[3];
  const float* W2 = (const float*)d_in[4];
  const float* b2 = (const float*)d_in[5];
  float* out = (float*)d_out;

  const int N = in_sizes[0] / 128;  // 100000
  const int E = in_sizes[1] / 2;    // 1600000
  const int NBK = (N + 127) >> 7;   // 782 buckets of 128 nodes
  const int SB = (E + 2047) / 2048; // 782 hist blocks (2048 edges each)
  const int G1 = (N + 63) / 64;     // gemm blocks

  char* ws = (char*)d_ws;
  size_t off = 0;
  auto take = [&](size_t bytes) -> void* {
    void* p = ws + off;
    off += (bytes + 255) & ~(size_t)255;
    return p;
  };
  int*    flag   = (int*)take(sizeof(int));
  int*    Hh     = (int*)take((size_t)NBK * SB * 4);    // 2.4 MB hist matrix
  int*    T      = (int*)take((size_t)NBK * 4);
  float*  dinv   = (float*)take((size_t)N * 4);
  int*    tmp_pk = (int*)take((size_t)E * 4);           // 6.4 MB
  int*    tmp_mt = (int*)take((size_t)E * 4);           // 6.4 MB
  int*    arena  = (int*)take((size_t)NBK * CAPB * 4);  // 9.6 MB
  __half* hsf    = (__half*)take((size_t)N * 64 * 2);   // f16 gather buffer
  __half* hh     = (__half*)take((size_t)N * 64 * 2);   // post layer-1 (f16)
  (void)ws_size; (void)n_in; (void)out_size;

  detect_i64_kernel<<<1, 256, 0, stream>>>((const unsigned int*)ei, 4096, flag);

  // A1: per-block hist + tmp streams || g = x@W1 (f16, MFMA).
  hist_gemm_kernel<<<SB + G1, 256, 0, stream>>>(
      ei, E, flag, Hh, SB, NBK, tmp_pk, tmp_mt, x, W1, hsf, N);

  // A2: exact per-(bucket,block) bases + bucket totals.
  scan_hist_kernel<<<NBK, 256, 0, stream>>>(Hh, SB, T);

  // A3: place edges at exact arena slots (atomic-free).
  place_kernel<<<((E + 3) / 4 + 255) / 256, 256, 0, stream>>>(
      tmp_pk, tmp_mt, Hh, SB, E, arena);

  // degrees -> dinv.
  count_dinv_kernel<<<NBK, 256, 0, stream>>>(T, arena, N, dinv);

  // h = relu(dinv[d]*(sum dinv[s]*g[s] + dinv[d]*g[d]) + b1)  -> f16
  agg_lds_kernel<true, true, __half><<<NBK, 512, 0, stream>>>(
      hsf, T, arena, dinv, b1, hh, N);

  // hs2 = (h @ W2) * dinv  (f16, MFMA)
  gemm2_kernel<<<G1, 256, 0, stream>>>((const _Float16*)hh, W2, dinv, hsf, N);

  // out = dinv[d]*(sum hs2[s] + hs2[d]) + b2
  agg_lds_kernel<false, false, float><<<NBK, 512, 0, stream>>>(
      hsf, T, arena, dinv, b2, out, N);
}

// Round 12
// 179.325 us; speedup vs baseline: 7.9774x; 7.9774x over previous
//
#include <hip/hip_runtime.h>
#include <hip/hip_fp16.h>

// ---------------------------------------------------------------------------
// 2-layer GCN: out = GCNConv2( relu(GCNConv1(x)) )
// GCNConv(x,W,b): h = x@W ; out[d] = dinv[d]*( sum_{s->d} h[s]*dinv[s] + h[d]*dinv[d] ) + b
// dinv = rsqrt(in-degree + 1) (self-loops).
//
// Build = counting sort with exact bases (zero global atomics):
//  A1 hist_gemm: per-block LDS hist over 128-node buckets -> H[bucket][block];
//     payload/meta to sequential tmp. gemm1 (x@W1 -> f16, MFMA) fused in.
//  A2 scan_hist: exact (bucket,block) bases + totals T.
//  A3 place: tmp -> packed per-bucket arena.  B cluster_csr: LDS-atomic
//     scatter into padded per-node CSR + counts + dinv.
// Aggregation: quarter-wave per node, 8 gathers in flight, and nodes are
// processed in DEGREE-SORTED order via perm[] (counting sort on degree,
// 65 bins, exact bases) so the 4 nodes in a wave have ~equal degree ->
// near-zero predication waste. (Round-10 lesson: per-edge LDS f32 atomics
// serialize catastrophically — 681us. Reverted to round-9 agg.)
// ---------------------------------------------------------------------------

#define CAP   64      // per-node CSR slots (max in-degree ~40 at 12 sigma)
#define CAPB  3072    // arena slots per 128-node bucket (mean ~2046)
#define BKMAX 1024
#define DBIN  65      // degree bins 0..64

typedef _Float16 f16x8 __attribute__((ext_vector_type(8)));
typedef float f32x4 __attribute__((ext_vector_type(4)));

struct alignas(8) H4 { __half2 a, b; };
__device__ inline H4 pack4(float x, float y, float z, float w) {
  H4 r; r.a = __floats2half2_rn(x, y); r.b = __floats2half2_rn(z, w); return r;
}

// Detect whether edge_index was stored as int64 (all high words of values <N
// are zero) or int32 (odd words are random node ids, nonzero w.h.p.).
__global__ void detect_i64_kernel(const unsigned int* __restrict__ w, int ncheck,
                                  int* __restrict__ flag) {
  __shared__ int nz;
  if (threadIdx.x == 0) nz = 0;
  __syncthreads();
  for (int i = threadIdx.x; i < ncheck; i += blockDim.x) {
    if (w[2 * i + 1] != 0u) nz = 1;
  }
  __syncthreads();
  if (threadIdx.x == 0) flag[0] = (nz == 0) ? 1 : 0;
}

// A1 fused with GEMM1. Blocks [0,SB): 2048 edges each -> LDS hist, tmp
// streams, H row. Blocks [SB, SB+G1): g = x @ W1 (unscaled f16, MFMA).
__global__ __launch_bounds__(256) void hist_gemm_kernel(
    const int* __restrict__ edges, int E, const int* __restrict__ flag,
    int* __restrict__ Hh, int SB, int nbk,
    int* __restrict__ tmp_pk, int* __restrict__ tmp_mt,
    const float* __restrict__ A, const float* __restrict__ W,
    __half* __restrict__ g, int n) {
  __shared__ __align__(16) char smem[34816];  // union: {Af,Wf} | hist
  const int t = threadIdx.x;
  const int bid = (int)blockIdx.x;

  if (bid < SB) {
    int* hist = (int*)smem;  // [BKMAX]
    const int f = flag[0];
    const int blk0 = bid * 2048;

    for (int i = t; i < nbk; i += 256) hist[i] = 0;
    __syncthreads();

    if (blk0 + 2048 <= E) {  // full block: 8 edges/thread, vector loads
      int sv[8], dv[8];
      if (f) {  // int64 storage: value in low word of each qword
#pragma unroll
        for (int u = 0; u < 4; ++u) {
          const int eg = blk0 + (u * 256 + t) * 2;  // pair of edges
          const int4 a = *(const int4*)&edges[2 * (size_t)eg];
          const int4 b = *(const int4*)&edges[2 * ((size_t)E + eg)];
          sv[u * 2] = a.x; sv[u * 2 + 1] = a.z;
          dv[u * 2] = b.x; dv[u * 2 + 1] = b.z;
        }
      } else {
#pragma unroll
        for (int u = 0; u < 2; ++u) {
          const int eg = blk0 + (u * 256 + t) * 4;
          const int4 a = *(const int4*)&edges[eg];
          const int4 b = *(const int4*)&edges[(size_t)E + eg];
          sv[u * 4] = a.x; sv[u * 4 + 1] = a.y; sv[u * 4 + 2] = a.z; sv[u * 4 + 3] = a.w;
          dv[u * 4] = b.x; dv[u * 4 + 1] = b.y; dv[u * 4 + 2] = b.z; dv[u * 4 + 3] = b.w;
        }
      }
      int pk[8], mt[8];
#pragma unroll
      for (int i = 0; i < 8; ++i) {
        const int bk = dv[i] >> 7;
        const int rk = atomicAdd(&hist[bk], 1);
        pk[i] = ((dv[i] & 127) << 17) | sv[i];
        mt[i] = bk | (rk << 10);
      }
      if (f) {
#pragma unroll
        for (int u = 0; u < 4; ++u) {
          const int eg = blk0 + (u * 256 + t) * 2;
          *(int2*)&tmp_pk[eg] = make_int2(pk[u * 2], pk[u * 2 + 1]);
          *(int2*)&tmp_mt[eg] = make_int2(mt[u * 2], mt[u * 2 + 1]);
        }
      } else {
        *(int4*)&tmp_pk[blk0 + t * 4]        = make_int4(pk[0], pk[1], pk[2], pk[3]);
        *(int4*)&tmp_pk[blk0 + 1024 + t * 4] = make_int4(pk[4], pk[5], pk[6], pk[7]);
        *(int4*)&tmp_mt[blk0 + t * 4]        = make_int4(mt[0], mt[1], mt[2], mt[3]);
        *(int4*)&tmp_mt[blk0 + 1024 + t * 4] = make_int4(mt[4], mt[5], mt[6], mt[7]);
      }
    } else {  // tail block
      for (int e = blk0 + t; e < E; e += 256) {
        const int s = f ? edges[2 * (size_t)e] : edges[e];
        const int d = f ? edges[2 * ((size_t)E + e)] : edges[(size_t)E + e];
        const int bk = d >> 7;
        const int rk = atomicAdd(&hist[bk], 1);
        tmp_pk[e] = ((d & 127) << 17) | s;
        tmp_mt[e] = bk | (rk << 10);
      }
    }
    __syncthreads();
    for (int i = t; i < nbk; i += 256) Hh[(size_t)i * SB + bid] = hist[i];
    return;
  }

  // ---------------- GEMM1 path (MFMA f16, K=128) ----------------
  _Float16 (*Af)[136] = (_Float16(*)[136])smem;            // A[row][k], +8 pad
  _Float16 (*Wf)[136] = (_Float16(*)[136])(smem + 17408);  // Wt[col][k]
  const int row0 = (bid - SB) * 64;

  {  // stage A tile (64x128 f32 -> f16), coalesced
    const int r = t >> 2, k0 = (t & 3) << 5;
    const int gr = row0 + r;
    if (gr < n) {
#pragma unroll
      for (int q = 0; q < 4; ++q) {
        float4 a = *(const float4*)&A[(size_t)gr * 128 + k0 + q * 8];
        float4 b = *(const float4*)&A[(size_t)gr * 128 + k0 + q * 8 + 4];
        f16x8 v;
        v[0] = (_Float16)a.x; v[1] = (_Float16)a.y; v[2] = (_Float16)a.z; v[3] = (_Float16)a.w;
        v[4] = (_Float16)b.x; v[5] = (_Float16)b.y; v[6] = (_Float16)b.z; v[7] = (_Float16)b.w;
        *(f16x8*)&Af[r][k0 + q * 8] = v;
      }
    } else {
      f16x8 z = {0, 0, 0, 0, 0, 0, 0, 0};
#pragma unroll
      for (int q = 0; q < 4; ++q) *(f16x8*)&Af[r][k0 + q * 8] = z;
    }
  }
  {  // stage W transposed (Wt[col][k]), coalesced per k-row
    const int c = t & 63, kq = t >> 6;
#pragma unroll
    for (int i = 0; i < 32; ++i)
      Wf[c][kq * 32 + i] = (_Float16)W[(size_t)(kq * 32 + i) * 64 + c];
  }
  __syncthreads();

  const int wid = t >> 6, lane = t & 63;
  const int lr = lane & 15, kg = lane >> 4;
  f32x4 acc[4] = {{0, 0, 0, 0}, {0, 0, 0, 0}, {0, 0, 0, 0}, {0, 0, 0, 0}};
#pragma unroll
  for (int kc = 0; kc < 4; ++kc) {
    f16x8 av = *(const f16x8*)&Af[wid * 16 + lr][kc * 32 + kg * 8];
#pragma unroll
    for (int ct = 0; ct < 4; ++ct) {
      f16x8 bv = *(const f16x8*)&Wf[ct * 16 + lr][kc * 32 + kg * 8];
      acc[ct] = __builtin_amdgcn_mfma_f32_16x16x32_f16(av, bv, acc[ct], 0, 0, 0);
    }
  }
#pragma unroll
  for (int ct = 0; ct < 4; ++ct) {
#pragma unroll
    for (int rg = 0; rg < 4; ++rg) {
      const int r = row0 + wid * 16 + kg * 4 + rg;
      if (r < n) g[(size_t)r * 64 + ct * 16 + lr] = (__half)(float)acc[ct][rg];
    }
  }
}

// A2: per-bucket exclusive scan of H row (SB entries) + bucket total T.
__global__ __launch_bounds__(256) void scan_hist_kernel(
    int* __restrict__ Hh, int SB, int* __restrict__ T) {
  __shared__ int sm[256];
  __shared__ int carry;
  const int b = blockIdx.x;
  const int t = threadIdx.x;
  if (t == 0) carry = 0;
  __syncthreads();
  int* __restrict__ row = Hh + (size_t)b * SB;
  for (int base = 0; base < SB; base += 256) {
    const int i = base + t;
    const int v = (i < SB) ? row[i] : 0;
    sm[t] = v;
    __syncthreads();
    for (int off = 1; off < 256; off <<= 1) {
      int u = (t >= off) ? sm[t - off] : 0;
      __syncthreads();
      sm[t] += u;
      __syncthreads();
    }
    const int excl = sm[t] - v + carry;
    if (i < SB) row[i] = excl;
    __syncthreads();
    if (t == 0) carry += sm[255];
    __syncthreads();
  }
  if (t == 0) T[b] = carry;
}

// A3: stream tmp, place each edge at its exact arena slot. No atomics.
__global__ __launch_bounds__(256) void place_kernel(
    const int* __restrict__ tmp_pk, const int* __restrict__ tmp_mt,
    const int* __restrict__ Hh, int SB, int E, int* __restrict__ arena) {
  const int e0 = ((int)blockIdx.x * 256 + (int)threadIdx.x) * 4;
  if (e0 >= E) return;
  const int blk = e0 >> 11;  // originating A1 block (2048-edge chunks)
  if (e0 + 4 <= E) {
    const int4 pk = *(const int4*)&tmp_pk[e0];
    const int4 mt = *(const int4*)&tmp_mt[e0];
    const int b0 = mt.x & 1023, b1 = mt.y & 1023, b2 = mt.z & 1023, b3 = mt.w & 1023;
    const int p0 = Hh[(size_t)b0 * SB + blk] + (mt.x >> 10);
    const int p1 = Hh[(size_t)b1 * SB + blk] + (mt.y >> 10);
    const int p2 = Hh[(size_t)b2 * SB + blk] + (mt.z >> 10);
    const int p3 = Hh[(size_t)b3 * SB + blk] + (mt.w >> 10);
    if (p0 < CAPB) arena[(size_t)b0 * CAPB + p0] = pk.x;
    if (p1 < CAPB) arena[(size_t)b1 * CAPB + p1] = pk.y;
    if (p2 < CAPB) arena[(size_t)b2 * CAPB + p2] = pk.z;
    if (p3 < CAPB) arena[(size_t)b3 * CAPB + p3] = pk.w;
  } else {
    for (int e = e0; e < E; ++e) {
      const int mt = tmp_mt[e];
      const int bk = mt & 1023;
      const int p = Hh[(size_t)bk * SB + blk] + (mt >> 10);
      if (p < CAPB) arena[(size_t)bk * CAPB + p] = tmp_pk[e];
    }
  }
}

// Pass B: one block (512 thr) per 128-node bucket. LDS-atomic ranks ->
// padded per-node CSR; emits counts + dinv.
__global__ __launch_bounds__(512) void cluster_csr_kernel(
    const int* __restrict__ T, const int* __restrict__ arena,
    int n, int* __restrict__ counts, float* __restrict__ dinv,
    int* __restrict__ csrp) {
  __shared__ int lc[128];
  const int b = blockIdx.x;
  const int t = threadIdx.x;
  if (t < 128) lc[t] = 0;
  __syncthreads();
  int cnt = T[b];
  if (cnt > CAPB) cnt = CAPB;
  const int* __restrict__ seg = &arena[(size_t)b * CAPB];
  for (int j = t; j < cnt; j += 512) {
    const int p = seg[j];
    const int dl = p >> 17;
    const int s = p & 131071;
    const int r = atomicAdd(&lc[dl], 1);
    if (r < CAP) csrp[((size_t)(b << 7) + dl) * CAP + r] = s;
  }
  __syncthreads();
  const int d = (b << 7) + t;
  if (t < 128 && d < n) {
    counts[d] = lc[t];
    dinv[d] = rsqrtf((float)(lc[t] + 1));
  }
}

// ---- degree-sort permutation (counting sort, exact bases, no hot atomics) --

// P1: per-block (2048 nodes) LDS hist over degree bins -> Hp[bin][block].
__global__ __launch_bounds__(256) void perm_hist_kernel(
    const int* __restrict__ counts, int n, int* __restrict__ Hp, int PB) {
  __shared__ int hist[DBIN];
  const int t = threadIdx.x;
  const int blk0 = (int)blockIdx.x * 2048;
  if (t < DBIN) hist[t] = 0;
  __syncthreads();
  for (int i = blk0 + t; i < blk0 + 2048 && i < n; i += 256) {
    int dg = counts[i];
    if (dg > 64) dg = 64;
    atomicAdd(&hist[dg], 1);
  }
  __syncthreads();
  if (t < DBIN) Hp[(size_t)t * PB + blockIdx.x] = hist[t];
}

// P2: single block, exclusive scan of the flattened Hp (bin-major, len DBIN*PB).
__global__ __launch_bounds__(256) void perm_scan_kernel(int* __restrict__ Hp, int len) {
  __shared__ int sm[256];
  __shared__ int carry;
  const int t = threadIdx.x;
  if (t == 0) carry = 0;
  __syncthreads();
  for (int base = 0; base < len; base += 256) {
    const int i = base + t;
    const int v = (i < len) ? Hp[i] : 0;
    sm[t] = v;
    __syncthreads();
    for (int off = 1; off < 256; off <<= 1) {
      int u = (t >= off) ? sm[t - off] : 0;
      __syncthreads();
      sm[t] += u;
      __syncthreads();
    }
    if (i < len) Hp[i] = sm[t] - v + carry;
    __syncthreads();
    if (t == 0) carry += sm[255];
    __syncthreads();
  }
}

// P3: re-histogram, place node ids at exact perm slots.
__global__ __launch_bounds__(256) void perm_place_kernel(
    const int* __restrict__ counts, int n, const int* __restrict__ Hp, int PB,
    int* __restrict__ perm) {
  __shared__ int hist[DBIN];
  const int t = threadIdx.x;
  const int blk0 = (int)blockIdx.x * 2048;
  if (t < DBIN) hist[t] = 0;
  __syncthreads();
  for (int i = blk0 + t; i < blk0 + 2048 && i < n; i += 256) {
    int dg = counts[i];
    if (dg > 64) dg = 64;
    const int rk = atomicAdd(&hist[dg], 1);
    perm[Hp[(size_t)dg * PB + blockIdx.x] + rk] = i;
  }
}

// GEMM2 (MFMA f16, K=64): hs2 = (h @ W2) * dinv[row], f16 in (h), f16 out.
__global__ __launch_bounds__(256) void gemm2_kernel(
    const _Float16* __restrict__ h, const float* __restrict__ W,
    const float* __restrict__ dinv, __half* __restrict__ out, int n) {
  __shared__ __align__(16) _Float16 Af[64][72];  // h[row][k], +8 pad
  __shared__ __align__(16) _Float16 Wf[64][72];  // Wt[col][k]
  const int t = threadIdx.x;
  const int row0 = blockIdx.x * 64;

  {  // stage h tile (f16 direct copy)
    const int r = t >> 2, k0 = (t & 3) << 4;
    const int gr = row0 + r;
    if (gr < n) {
      *(f16x8*)&Af[r][k0] = *(const f16x8*)&h[(size_t)gr * 64 + k0];
      *(f16x8*)&Af[r][k0 + 8] = *(const f16x8*)&h[(size_t)gr * 64 + k0 + 8];
    } else {
      f16x8 z = {0, 0, 0, 0, 0, 0, 0, 0};
      *(f16x8*)&Af[r][k0] = z;
      *(f16x8*)&Af[r][k0 + 8] = z;
    }
  }
  {  // stage W2 transposed
    const int c = t & 63, kq = t >> 6;
#pragma unroll
    for (int i = 0; i < 16; ++i)
      Wf[c][kq * 16 + i] = (_Float16)W[(size_t)(kq * 16 + i) * 64 + c];
  }
  __syncthreads();

  const int wid = t >> 6, lane = t & 63;
  const int lr = lane & 15, kg = lane >> 4;
  f32x4 acc[4] = {{0, 0, 0, 0}, {0, 0, 0, 0}, {0, 0, 0, 0}, {0, 0, 0, 0}};
#pragma unroll
  for (int kc = 0; kc < 2; ++kc) {
    f16x8 av = *(const f16x8*)&Af[wid * 16 + lr][kc * 32 + kg * 8];
#pragma unroll
    for (int ct = 0; ct < 4; ++ct) {
      f16x8 bv = *(const f16x8*)&Wf[ct * 16 + lr][kc * 32 + kg * 8];
      acc[ct] = __builtin_amdgcn_mfma_f32_16x16x32_f16(av, bv, acc[ct], 0, 0, 0);
    }
  }
  float sc[4];
#pragma unroll
  for (int rg = 0; rg < 4; ++rg) {
    const int r = row0 + wid * 16 + kg * 4 + rg;
    sc[rg] = (r < n) ? dinv[r] : 0.f;
  }
#pragma unroll
  for (int ct = 0; ct < 4; ++ct) {
#pragma unroll
    for (int rg = 0; rg < 4; ++rg) {
      const int r = row0 + wid * 16 + kg * 4 + rg;
      if (r < n) out[(size_t)r * 64 + ct * 16 + lr] = (__half)((float)acc[ct][rg] * sc[rg]);
    }
  }
}

// Aggregation over padded CSR rows, degree-sorted order: node = perm[idx].
// 4 nodes per wave (quarter-wave each, 16 lanes x 8B = one 128B f16 row);
// perm makes the 4 degrees ~equal -> near-zero predicated waste. Unroll 8.
template <bool EDGE_SCALE, bool RELU, typename OUT>
__global__ __launch_bounds__(256) void agg_kernel(
    const __half* __restrict__ hs, const int* __restrict__ counts,
    const int* __restrict__ csrp, const float* __restrict__ dinv,
    const float* __restrict__ bias, const int* __restrict__ perm,
    OUT* __restrict__ out, int n) {
  const int wid = blockIdx.x * 4 + ((int)threadIdx.x >> 6);
  if (wid * 4 >= n) return;
  const int lane = (int)threadIdx.x & 63;
  const int q = lane >> 4;   // quarter 0..3 -> node slot
  const int ql = lane & 15;  // lane in quarter -> channel group
  const int idx = wid * 4 + q;
  const bool active = idx < n;
  const int dc = perm[active ? idx : n - 1];

  int len = counts[dc];
  if (len > CAP) len = CAP;
  if (!active) len = 0;
  const int* __restrict__ row = &csrp[(size_t)dc * CAP];
  const float dd = dinv[dc];

  H4 sv = *(const H4*)&hs[(size_t)dc * 64 + (ql << 2)];
  float2 s01 = __half22float2(sv.a), s23 = __half22float2(sv.b);
  const float ws = EDGE_SCALE ? dd : 1.f;
  float a0 = ws * s01.x, a1 = ws * s01.y, a2 = ws * s23.x, a3 = ws * s23.y;

  for (int j = 0; __any(j < len); j += 8) {
    int sidx[8];
    bool pr[8];
#pragma unroll
    for (int u = 0; u < 8; ++u) {
      pr[u] = (j + u) < len;
      sidx[u] = pr[u] ? row[j + u] : dc;
    }
    H4 v[8];
#pragma unroll
    for (int u = 0; u < 8; ++u) v[u] = *(const H4*)&hs[(size_t)sidx[u] * 64 + (ql << 2)];
#pragma unroll
    for (int u = 0; u < 8; ++u) {
      float w = pr[u] ? (EDGE_SCALE ? dinv[sidx[u]] : 1.f) : 0.f;
      float2 f = __half22float2(v[u].a), g = __half22float2(v[u].b);
      a0 = fmaf(w, f.x, a0); a1 = fmaf(w, f.y, a1);
      a2 = fmaf(w, g.x, a2); a3 = fmaf(w, g.y, a3);
    }
  }

  if (active) {
    const float4 b4 = *(const float4*)&bias[ql << 2];
    float4 o;
    o.x = fmaf(a0, dd, b4.x); o.y = fmaf(a1, dd, b4.y);
    o.z = fmaf(a2, dd, b4.z); o.w = fmaf(a3, dd, b4.w);
    if (RELU) {
      o.x = fmaxf(o.x, 0.f); o.y = fmaxf(o.y, 0.f);
      o.z = fmaxf(o.z, 0.f); o.w = fmaxf(o.w, 0.f);
    }
    if constexpr (sizeof(OUT) == 2) {
      *(H4*)&out[(size_t)dc * 64 + (ql << 2)] = pack4(o.x, o.y, o.z, o.w);
    } else {
      *(float4*)&out[(size_t)dc * 64 + (ql << 2)] = o;
    }
  }
}

extern "C" void kernel_launch(void* const* d_in, const int* in_sizes, int n_in,
                              void* d_out, int out_size, void* d_ws, size_t ws_size,
                              hipStream_t stream) {
  const float* x  = (const float*)d_in[0];
  const int*   ei = (const int*)d_in[1];
  const float* W1 = (const float*)d_in[2];
  const float* b1 = (const float*)d_in[3];
  const float* W2 = (const float*)d_in[4];
  const float* b2 = (const float*)d_in[5];
  float* out = (float*)d_out;

  const int N = in_sizes[0] / 128;  // 100000
  const int E = in_sizes[1] / 2;    // 1600000
  const int NBK = (N + 127) >> 7;   // 782 buckets of 128 nodes
  const int SB = (E + 2047) / 2048; // 782 hist blocks (2048 edges each)
  const int G1 = (N + 63) / 64;     // gemm blocks
  const int PB = (N + 2047) / 2048; // 49 perm blocks

  char* ws = (char*)d_ws;
  size_t off = 0;
  auto take = [&](size_t bytes) -> void* {
    void* p = ws + off;
    off += (bytes + 255) & ~(size_t)255;
    return p;
  };
  int*    flag   = (int*)take(sizeof(int));
  int*    Hh     = (int*)take((size_t)NBK * SB * 4);    // 2.4 MB hist matrix
  int*    T      = (int*)take((size_t)NBK * 4);
  int*    counts = (int*)take((size_t)N * 4);
  float*  dinv   = (float*)take((size_t)N * 4);
  int*    Hp     = (int*)take((size_t)DBIN * PB * 4);   // degree-hist matrix
  int*    perm   = (int*)take((size_t)N * 4);
  int*    tmp_pk = (int*)take((size_t)E * 4);           // 6.4 MB
  int*    tmp_mt = (int*)take((size_t)E * 4);           // 6.4 MB
  int*    arena  = (int*)take((size_t)NBK * CAPB * 4);  // 9.6 MB
  int*    csrp   = (int*)take((size_t)N * CAP * 4);     // 25.6 MB
  __half* hsf    = (__half*)take((size_t)N * 64 * 2);   // f16 gather buffer
  __half* hh     = (__half*)take((size_t)N * 64 * 2);   // post layer-1 (f16)
  (void)ws_size; (void)n_in; (void)out_size;

  detect_i64_kernel<<<1, 256, 0, stream>>>((const unsigned int*)ei, 4096, flag);

  // A1: per-block hist + tmp streams || g = x@W1 (f16, MFMA).
  hist_gemm_kernel<<<SB + G1, 256, 0, stream>>>(
      ei, E, flag, Hh, SB, NBK, tmp_pk, tmp_mt, x, W1, hsf, N);

  // A2: exact per-(bucket,block) bases + bucket totals.
  scan_hist_kernel<<<NBK, 256, 0, stream>>>(Hh, SB, T);

  // A3: place edges at exact arena slots (atomic-free).
  place_kernel<<<((E + 3) / 4 + 255) / 256, 256, 0, stream>>>(
      tmp_pk, tmp_mt, Hh, SB, E, arena);

  // B: per-bucket LDS-atomic CSR + counts + dinv.
  cluster_csr_kernel<<<NBK, 512, 0, stream>>>(T, arena, N, counts, dinv, csrp);

  // degree-sort permutation (counting sort on degree).
  perm_hist_kernel<<<PB, 256, 0, stream>>>(counts, N, Hp, PB);
  perm_scan_kernel<<<1, 256, 0, stream>>>(Hp, DBIN * PB);
  perm_place_kernel<<<PB, 256, 0, stream>>>(counts, N, Hp, PB, perm);

  // h = relu(dinv[d]*(sum dinv[s]*g[s] + dinv[d]*g[d]) + b1)  -> f16
  agg_kernel<true, true, __half><<<(N + 15) / 16, 256, 0, stream>>>(
      hsf, counts, csrp, dinv, b1, perm, hh, N);

  // hs2 = (h @ W2) * dinv  (f16, MFMA)
  gemm2_kernel<<<G1, 256, 0, stream>>>((const _Float16*)hh, W2, dinv, hsf, N);

  // out = dinv[d]*(sum hs2[s] + hs2[d]) + b2
  agg_kernel<false, false, float><<<(N + 15) / 16, 256, 0, stream>>>(
      hsf, counts, csrp, dinv, b2, perm, out, N);
}

// Round 13
// 154.515 us; speedup vs baseline: 9.2583x; 1.1606x over previous
//
#include <hip/hip_runtime.h>
#include <hip/hip_fp16.h>

// ---------------------------------------------------------------------------
// 2-layer GCN: out = GCNConv2( relu(GCNConv1(x)) )
// GCNConv(x,W,b): h = x@W ; out[d] = dinv[d]*( sum_{s->d} h[s]*dinv[s] + h[d]*dinv[d] ) + b
// dinv = rsqrt(in-degree + 1) (self-loops).
//
// Build = counting sort with exact bases (zero global atomics):
//  A1 hist_gemm: per-block LDS hist over 128-node buckets -> H[bucket][block];
//     payload/meta to sequential tmp. gemm1 (x@W1 -> f16, MFMA) fused in.
//  A2 scan_hist: exact (bucket,block) bases + totals T.
//  A3 place: tmp -> packed per-bucket arena.
//  B  cluster_csr: LDS-atomic scatter into padded per-node CSR + counts+dinv.
// Aggregation: 8 nodes per wave, 8-lane groups, 16 B/lane H8 gathers
// (1 KB per instruction, 8 independent streams x unroll 8 in flight).
// (History: LDS f32 atomics = 9x regression, r10; degree-sort perm = net
// regression from scattered out-writes, r11.)
// ---------------------------------------------------------------------------

#define CAP   64      // per-node CSR slots (max in-degree ~40 at 12 sigma)
#define CAPB  3072    // arena slots per 128-node bucket (mean ~2046)
#define BKMAX 1024

typedef _Float16 f16x8 __attribute__((ext_vector_type(8)));
typedef float f32x4 __attribute__((ext_vector_type(4)));

struct alignas(8) H4 { __half2 a, b; };
struct alignas(16) H8 { __half2 a, b, c, d; };
__device__ inline H4 pack4(float x, float y, float z, float w) {
  H4 r; r.a = __floats2half2_rn(x, y); r.b = __floats2half2_rn(z, w); return r;
}

// Detect whether edge_index was stored as int64 (all high words of values <N
// are zero) or int32 (odd words are random node ids, nonzero w.h.p.).
__global__ void detect_i64_kernel(const unsigned int* __restrict__ w, int ncheck,
                                  int* __restrict__ flag) {
  __shared__ int nz;
  if (threadIdx.x == 0) nz = 0;
  __syncthreads();
  for (int i = threadIdx.x; i < ncheck; i += blockDim.x) {
    if (w[2 * i + 1] != 0u) nz = 1;
  }
  __syncthreads();
  if (threadIdx.x == 0) flag[0] = (nz == 0) ? 1 : 0;
}

// A1 fused with GEMM1. Blocks [0,SB): 2048 edges each -> LDS hist, tmp
// streams, H row. Blocks [SB, SB+G1): g = x @ W1 (unscaled f16, MFMA).
__global__ __launch_bounds__(256) void hist_gemm_kernel(
    const int* __restrict__ edges, int E, const int* __restrict__ flag,
    int* __restrict__ Hh, int SB, int nbk,
    int* __restrict__ tmp_pk, int* __restrict__ tmp_mt,
    const float* __restrict__ A, const float* __restrict__ W,
    __half* __restrict__ g, int n) {
  __shared__ __align__(16) char smem[34816];  // union: {Af,Wf} | hist
  const int t = threadIdx.x;
  const int bid = (int)blockIdx.x;

  if (bid < SB) {
    int* hist = (int*)smem;  // [BKMAX]
    const int f = flag[0];
    const int blk0 = bid * 2048;

    for (int i = t; i < nbk; i += 256) hist[i] = 0;
    __syncthreads();

    if (blk0 + 2048 <= E) {  // full block: 8 edges/thread, vector loads
      int sv[8], dv[8];
      if (f) {  // int64 storage: value in low word of each qword
#pragma unroll
        for (int u = 0; u < 4; ++u) {
          const int eg = blk0 + (u * 256 + t) * 2;  // pair of edges
          const int4 a = *(const int4*)&edges[2 * (size_t)eg];
          const int4 b = *(const int4*)&edges[2 * ((size_t)E + eg)];
          sv[u * 2] = a.x; sv[u * 2 + 1] = a.z;
          dv[u * 2] = b.x; dv[u * 2 + 1] = b.z;
        }
      } else {
#pragma unroll
        for (int u = 0; u < 2; ++u) {
          const int eg = blk0 + (u * 256 + t) * 4;
          const int4 a = *(const int4*)&edges[eg];
          const int4 b = *(const int4*)&edges[(size_t)E + eg];
          sv[u * 4] = a.x; sv[u * 4 + 1] = a.y; sv[u * 4 + 2] = a.z; sv[u * 4 + 3] = a.w;
          dv[u * 4] = b.x; dv[u * 4 + 1] = b.y; dv[u * 4 + 2] = b.z; dv[u * 4 + 3] = b.w;
        }
      }
      int pk[8], mt[8];
#pragma unroll
      for (int i = 0; i < 8; ++i) {
        const int bk = dv[i] >> 7;
        const int rk = atomicAdd(&hist[bk], 1);
        pk[i] = ((dv[i] & 127) << 17) | sv[i];
        mt[i] = bk | (rk << 10);
      }
      if (f) {
#pragma unroll
        for (int u = 0; u < 4; ++u) {
          const int eg = blk0 + (u * 256 + t) * 2;
          *(int2*)&tmp_pk[eg] = make_int2(pk[u * 2], pk[u * 2 + 1]);
          *(int2*)&tmp_mt[eg] = make_int2(mt[u * 2], mt[u * 2 + 1]);
        }
      } else {
        *(int4*)&tmp_pk[blk0 + t * 4]        = make_int4(pk[0], pk[1], pk[2], pk[3]);
        *(int4*)&tmp_pk[blk0 + 1024 + t * 4] = make_int4(pk[4], pk[5], pk[6], pk[7]);
        *(int4*)&tmp_mt[blk0 + t * 4]        = make_int4(mt[0], mt[1], mt[2], mt[3]);
        *(int4*)&tmp_mt[blk0 + 1024 + t * 4] = make_int4(mt[4], mt[5], mt[6], mt[7]);
      }
    } else {  // tail block
      for (int e = blk0 + t; e < E; e += 256) {
        const int s = f ? edges[2 * (size_t)e] : edges[e];
        const int d = f ? edges[2 * ((size_t)E + e)] : edges[(size_t)E + e];
        const int bk = d >> 7;
        const int rk = atomicAdd(&hist[bk], 1);
        tmp_pk[e] = ((d & 127) << 17) | s;
        tmp_mt[e] = bk | (rk << 10);
      }
    }
    __syncthreads();
    for (int i = t; i < nbk; i += 256) Hh[(size_t)i * SB + bid] = hist[i];
    return;
  }

  // ---------------- GEMM1 path (MFMA f16, K=128) ----------------
  _Float16 (*Af)[136] = (_Float16(*)[136])smem;            // A[row][k], +8 pad
  _Float16 (*Wf)[136] = (_Float16(*)[136])(smem + 17408);  // Wt[col][k]
  const int row0 = (bid - SB) * 64;

  {  // stage A tile (64x128 f32 -> f16), coalesced
    const int r = t >> 2, k0 = (t & 3) << 5;
    const int gr = row0 + r;
    if (gr < n) {
#pragma unroll
      for (int q = 0; q < 4; ++q) {
        float4 a = *(const float4*)&A[(size_t)gr * 128 + k0 + q * 8];
        float4 b = *(const float4*)&A[(size_t)gr * 128 + k0 + q * 8 + 4];
        f16x8 v;
        v[0] = (_Float16)a.x; v[1] = (_Float16)a.y; v[2] = (_Float16)a.z; v[3] = (_Float16)a.w;
        v[4] = (_Float16)b.x; v[5] = (_Float16)b.y; v[6] = (_Float16)b.z; v[7] = (_Float16)b.w;
        *(f16x8*)&Af[r][k0 + q * 8] = v;
      }
    } else {
      f16x8 z = {0, 0, 0, 0, 0, 0, 0, 0};
#pragma unroll
      for (int q = 0; q < 4; ++q) *(f16x8*)&Af[r][k0 + q * 8] = z;
    }
  }
  {  // stage W transposed (Wt[col][k]), coalesced per k-row
    const int c = t & 63, kq = t >> 6;
#pragma unroll
    for (int i = 0; i < 32; ++i)
      Wf[c][kq * 32 + i] = (_Float16)W[(size_t)(kq * 32 + i) * 64 + c];
  }
  __syncthreads();

  const int wid = t >> 6, lane = t & 63;
  const int lr = lane & 15, kg = lane >> 4;
  f32x4 acc[4] = {{0, 0, 0, 0}, {0, 0, 0, 0}, {0, 0, 0, 0}, {0, 0, 0, 0}};
#pragma unroll
  for (int kc = 0; kc < 4; ++kc) {
    f16x8 av = *(const f16x8*)&Af[wid * 16 + lr][kc * 32 + kg * 8];
#pragma unroll
    for (int ct = 0; ct < 4; ++ct) {
      f16x8 bv = *(const f16x8*)&Wf[ct * 16 + lr][kc * 32 + kg * 8];
      acc[ct] = __builtin_amdgcn_mfma_f32_16x16x32_f16(av, bv, acc[ct], 0, 0, 0);
    }
  }
#pragma unroll
  for (int ct = 0; ct < 4; ++ct) {
#pragma unroll
    for (int rg = 0; rg < 4; ++rg) {
      const int r = row0 + wid * 16 + kg * 4 + rg;
      if (r < n) g[(size_t)r * 64 + ct * 16 + lr] = (__half)(float)acc[ct][rg];
    }
  }
}

// A2: per-bucket exclusive scan of H row (SB entries) + bucket total T.
__global__ __launch_bounds__(256) void scan_hist_kernel(
    int* __restrict__ Hh, int SB, int* __restrict__ T) {
  __shared__ int sm[256];
  __shared__ int carry;
  const int b = blockIdx.x;
  const int t = threadIdx.x;
  if (t == 0) carry = 0;
  __syncthreads();
  int* __restrict__ row = Hh + (size_t)b * SB;
  for (int base = 0; base < SB; base += 256) {
    const int i = base + t;
    const int v = (i < SB) ? row[i] : 0;
    sm[t] = v;
    __syncthreads();
    for (int off = 1; off < 256; off <<= 1) {
      int u = (t >= off) ? sm[t - off] : 0;
      __syncthreads();
      sm[t] += u;
      __syncthreads();
    }
    const int excl = sm[t] - v + carry;
    if (i < SB) row[i] = excl;
    __syncthreads();
    if (t == 0) carry += sm[255];
    __syncthreads();
  }
  if (t == 0) T[b] = carry;
}

// A3: stream tmp, place each edge at its exact arena slot. No atomics.
__global__ __launch_bounds__(256) void place_kernel(
    const int* __restrict__ tmp_pk, const int* __restrict__ tmp_mt,
    const int* __restrict__ Hh, int SB, int E, int* __restrict__ arena) {
  const int e0 = ((int)blockIdx.x * 256 + (int)threadIdx.x) * 4;
  if (e0 >= E) return;
  const int blk = e0 >> 11;  // originating A1 block (2048-edge chunks)
  if (e0 + 4 <= E) {
    const int4 pk = *(const int4*)&tmp_pk[e0];
    const int4 mt = *(const int4*)&tmp_mt[e0];
    const int b0 = mt.x & 1023, b1 = mt.y & 1023, b2 = mt.z & 1023, b3 = mt.w & 1023;
    const int p0 = Hh[(size_t)b0 * SB + blk] + (mt.x >> 10);
    const int p1 = Hh[(size_t)b1 * SB + blk] + (mt.y >> 10);
    const int p2 = Hh[(size_t)b2 * SB + blk] + (mt.z >> 10);
    const int p3 = Hh[(size_t)b3 * SB + blk] + (mt.w >> 10);
    if (p0 < CAPB) arena[(size_t)b0 * CAPB + p0] = pk.x;
    if (p1 < CAPB) arena[(size_t)b1 * CAPB + p1] = pk.y;
    if (p2 < CAPB) arena[(size_t)b2 * CAPB + p2] = pk.z;
    if (p3 < CAPB) arena[(size_t)b3 * CAPB + p3] = pk.w;
  } else {
    for (int e = e0; e < E; ++e) {
      const int mt = tmp_mt[e];
      const int bk = mt & 1023;
      const int p = Hh[(size_t)bk * SB + blk] + (mt >> 10);
      if (p < CAPB) arena[(size_t)bk * CAPB + p] = tmp_pk[e];
    }
  }
}

// Pass B: one block (512 thr) per 128-node bucket. LDS-atomic ranks ->
// padded per-node CSR; emits counts + dinv.
__global__ __launch_bounds__(512) void cluster_csr_kernel(
    const int* __restrict__ T, const int* __restrict__ arena,
    int n, int* __restrict__ counts, float* __restrict__ dinv,
    int* __restrict__ csrp) {
  __shared__ int lc[128];
  const int b = blockIdx.x;
  const int t = threadIdx.x;
  if (t < 128) lc[t] = 0;
  __syncthreads();
  int cnt = T[b];
  if (cnt > CAPB) cnt = CAPB;
  const int* __restrict__ seg = &arena[(size_t)b * CAPB];
  for (int j = t; j < cnt; j += 512) {
    const int p = seg[j];
    const int dl = p >> 17;
    const int s = p & 131071;
    const int r = atomicAdd(&lc[dl], 1);
    if (r < CAP) csrp[((size_t)(b << 7) + dl) * CAP + r] = s;
  }
  __syncthreads();
  const int d = (b << 7) + t;
  if (t < 128 && d < n) {
    counts[d] = lc[t];
    dinv[d] = rsqrtf((float)(lc[t] + 1));
  }
}

// GEMM2 (MFMA f16, K=64): hs2 = (h @ W2) * dinv[row], f16 in (h), f16 out.
__global__ __launch_bounds__(256) void gemm2_kernel(
    const _Float16* __restrict__ h, const float* __restrict__ W,
    const float* __restrict__ dinv, __half* __restrict__ out, int n) {
  __shared__ __align__(16) _Float16 Af[64][72];  // h[row][k], +8 pad
  __shared__ __align__(16) _Float16 Wf[64][72];  // Wt[col][k]
  const int t = threadIdx.x;
  const int row0 = blockIdx.x * 64;

  {  // stage h tile (f16 direct copy)
    const int r = t >> 2, k0 = (t & 3) << 4;
    const int gr = row0 + r;
    if (gr < n) {
      *(f16x8*)&Af[r][k0] = *(const f16x8*)&h[(size_t)gr * 64 + k0];
      *(f16x8*)&Af[r][k0 + 8] = *(const f16x8*)&h[(size_t)gr * 64 + k0 + 8];
    } else {
      f16x8 z = {0, 0, 0, 0, 0, 0, 0, 0};
      *(f16x8*)&Af[r][k0] = z;
      *(f16x8*)&Af[r][k0 + 8] = z;
    }
  }
  {  // stage W2 transposed
    const int c = t & 63, kq = t >> 6;
#pragma unroll
    for (int i = 0; i < 16; ++i)
      Wf[c][kq * 16 + i] = (_Float16)W[(size_t)(kq * 16 + i) * 64 + c];
  }
  __syncthreads();

  const int wid = t >> 6, lane = t & 63;
  const int lr = lane & 15, kg = lane >> 4;
  f32x4 acc[4] = {{0, 0, 0, 0}, {0, 0, 0, 0}, {0, 0, 0, 0}, {0, 0, 0, 0}};
#pragma unroll
  for (int kc = 0; kc < 2; ++kc) {
    f16x8 av = *(const f16x8*)&Af[wid * 16 + lr][kc * 32 + kg * 8];
#pragma unroll
    for (int ct = 0; ct < 4; ++ct) {
      f16x8 bv = *(const f16x8*)&Wf[ct * 16 + lr][kc * 32 + kg * 8];
      acc[ct] = __builtin_amdgcn_mfma_f32_16x16x32_f16(av, bv, acc[ct], 0, 0, 0);
    }
  }
  float sc[4];
#pragma unroll
  for (int rg = 0; rg < 4; ++rg) {
    const int r = row0 + wid * 16 + kg * 4 + rg;
    sc[rg] = (r < n) ? dinv[r] : 0.f;
  }
#pragma unroll
  for (int ct = 0; ct < 4; ++ct) {
#pragma unroll
    for (int rg = 0; rg < 4; ++rg) {
      const int r = row0 + wid * 16 + kg * 4 + rg;
      if (r < n) out[(size_t)r * 64 + ct * 16 + lr] = (__half)((float)acc[ct][rg] * sc[rg]);
    }
  }
}

// Aggregation over padded CSR rows: 8 nodes per wave; 8-lane group per node,
// lane covers channels [gl*8, gl*8+8) via one 16B H8 load -> 1KB gathered per
// instruction, 8 independent node streams x unroll 8 in flight per wave.
template <bool EDGE_SCALE, bool RELU, typename OUT>
__global__ __launch_bounds__(256) void agg_kernel(
    const __half* __restrict__ hs, const int* __restrict__ counts,
    const int* __restrict__ csrp, const float* __restrict__ dinv,
    const float* __restrict__ bias, OUT* __restrict__ out, int n) {
  const int wid = blockIdx.x * 4 + ((int)threadIdx.x >> 6);
  if (wid * 8 >= n) return;
  const int lane = (int)threadIdx.x & 63;
  const int og = lane >> 3;  // node slot 0..7
  const int gl = lane & 7;   // channel group: channels gl*8 .. gl*8+8
  const int d = wid * 8 + og;
  const bool active = d < n;
  const int dc = active ? d : n - 1;

  int len = counts[dc];
  if (len > CAP) len = CAP;
  if (!active) len = 0;
  const int* __restrict__ row = &csrp[(size_t)dc * CAP];
  const float dd = dinv[dc];

  H8 sv = *(const H8*)&hs[(size_t)dc * 64 + (gl << 3)];
  const float ws = EDGE_SCALE ? dd : 1.f;
  float acc[8];
  {
    float2 f0 = __half22float2(sv.a), f1 = __half22float2(sv.b);
    float2 f2 = __half22float2(sv.c), f3 = __half22float2(sv.d);
    acc[0] = ws * f0.x; acc[1] = ws * f0.y; acc[2] = ws * f1.x; acc[3] = ws * f1.y;
    acc[4] = ws * f2.x; acc[5] = ws * f2.y; acc[6] = ws * f3.x; acc[7] = ws * f3.y;
  }

  for (int j = 0; __any(j < len); j += 8) {
    int sidx[8];
    bool pr[8];
#pragma unroll
    for (int u = 0; u < 8; ++u) {
      pr[u] = (j + u) < len;
      sidx[u] = pr[u] ? row[j + u] : dc;
    }
    H8 v[8];
#pragma unroll
    for (int u = 0; u < 8; ++u) v[u] = *(const H8*)&hs[(size_t)sidx[u] * 64 + (gl << 3)];
#pragma unroll
    for (int u = 0; u < 8; ++u) {
      const float w = pr[u] ? (EDGE_SCALE ? dinv[sidx[u]] : 1.f) : 0.f;
      float2 g0 = __half22float2(v[u].a), g1 = __half22float2(v[u].b);
      float2 g2 = __half22float2(v[u].c), g3 = __half22float2(v[u].d);
      acc[0] = fmaf(w, g0.x, acc[0]); acc[1] = fmaf(w, g0.y, acc[1]);
      acc[2] = fmaf(w, g1.x, acc[2]); acc[3] = fmaf(w, g1.y, acc[3]);
      acc[4] = fmaf(w, g2.x, acc[4]); acc[5] = fmaf(w, g2.y, acc[5]);
      acc[6] = fmaf(w, g3.x, acc[6]); acc[7] = fmaf(w, g3.y, acc[7]);
    }
  }

  if (active) {
    const float4 b0 = *(const float4*)&bias[gl << 3];
    const float4 b1 = *(const float4*)&bias[(gl << 3) + 4];
    float o[8];
    o[0] = fmaf(acc[0], dd, b0.x); o[1] = fmaf(acc[1], dd, b0.y);
    o[2] = fmaf(acc[2], dd, b0.z); o[3] = fmaf(acc[3], dd, b0.w);
    o[4] = fmaf(acc[4], dd, b1.x); o[5] = fmaf(acc[5], dd, b1.y);
    o[6] = fmaf(acc[6], dd, b1.z); o[7] = fmaf(acc[7], dd, b1.w);
    if (RELU) {
#pragma unroll
      for (int c = 0; c < 8; ++c) o[c] = fmaxf(o[c], 0.f);
    }
    if constexpr (sizeof(OUT) == 2) {
      H8 hv;
      hv.a = __floats2half2_rn(o[0], o[1]); hv.b = __floats2half2_rn(o[2], o[3]);
      hv.c = __floats2half2_rn(o[4], o[5]); hv.d = __floats2half2_rn(o[6], o[7]);
      *(H8*)&out[(size_t)d * 64 + (gl << 3)] = hv;
    } else {
      *(float4*)&out[(size_t)d * 64 + (gl << 3)] = make_float4(o[0], o[1], o[2], o[3]);
      *(float4*)&out[(size_t)d * 64 + (gl << 3) + 4] = make_float4(o[4], o[5], o[6], o[7]);
    }
  }
}

extern "C" void kernel_launch(void* const* d_in, const int* in_sizes, int n_in,
                              void* d_out, int out_size, void* d_ws, size_t ws_size,
                              hipStream_t stream) {
  const float* x  = (const float*)d_in[0];
  const int*   ei = (const int*)d_in[1];
  const float* W1 = (const float*)d_in[2];
  const float* b1 = (const float*)d_in[3];
  const float* W2 = (const float*)d_in[4];
  const float* b2 = (const float*)d_in[5];
  float* out = (float*)d_out;

  const int N = in_sizes[0] / 128;  // 100000
  const int E = in_sizes[1] / 2;    // 1600000
  const int NBK = (N + 127) >> 7;   // 782 buckets of 128 nodes
  const int SB = (E + 2047) / 2048; // 782 hist blocks (2048 edges each)
  const int G1 = (N + 63) / 64;     // gemm blocks

  char* ws = (char*)d_ws;
  size_t off = 0;
  auto take = [&](size_t bytes) -> void* {
    void* p = ws + off;
    off += (bytes + 255) & ~(size_t)255;
    return p;
  };
  int*    flag   = (int*)take(sizeof(int));
  int*    Hh     = (int*)take((size_t)NBK * SB * 4);    // 2.4 MB hist matrix
  int*    T      = (int*)take((size_t)NBK * 4);
  int*    counts = (int*)take((size_t)N * 4);
  float*  dinv   = (float*)take((size_t)N * 4);
  int*    tmp_pk = (int*)take((size_t)E * 4);           // 6.4 MB
  int*    tmp_mt = (int*)take((size_t)E * 4);           // 6.4 MB
  int*    arena  = (int*)take((size_t)NBK * CAPB * 4);  // 9.6 MB
  int*    csrp   = (int*)take((size_t)N * CAP * 4);     // 25.6 MB
  __half* hsf    = (__half*)take((size_t)N * 64 * 2);   // f16 gather buffer
  __half* hh     = (__half*)take((size_t)N * 64 * 2);   // post layer-1 (f16)
  (void)ws_size; (void)n_in; (void)out_size;

  detect_i64_kernel<<<1, 256, 0, stream>>>((const unsigned int*)ei, 4096, flag);

  // A1: per-block hist + tmp streams || g = x@W1 (f16, MFMA).
  hist_gemm_kernel<<<SB + G1, 256, 0, stream>>>(
      ei, E, flag, Hh, SB, NBK, tmp_pk, tmp_mt, x, W1, hsf, N);

  // A2: exact per-(bucket,block) bases + bucket totals.
  scan_hist_kernel<<<NBK, 256, 0, stream>>>(Hh, SB, T);

  // A3: place edges at exact arena slots (atomic-free).
  place_kernel<<<((E + 3) / 4 + 255) / 256, 256, 0, stream>>>(
      tmp_pk, tmp_mt, Hh, SB, E, arena);

  // B: per-bucket LDS-atomic CSR + counts + dinv.
  cluster_csr_kernel<<<NBK, 512, 0, stream>>>(T, arena, N, counts, dinv, csrp);

  // h = relu(dinv[d]*(sum dinv[s]*g[s] + dinv[d]*g[d]) + b1)  -> f16
  agg_kernel<true, true, __half><<<(N + 31) / 32, 256, 0, stream>>>(
      hsf, counts, csrp, dinv, b1, hh, N);

  // hs2 = (h @ W2) * dinv  (f16, MFMA)
  gemm2_kernel<<<G1, 256, 0, stream>>>((const _Float16*)hh, W2, dinv, hsf, N);

  // out = dinv[d]*(sum hs2[s] + hs2[d]) + b2
  agg_kernel<false, false, float><<<(N + 31) / 32, 256, 0, stream>>>(
      hsf, counts, csrp, dinv, b2, out, N);
}

// Round 14
// 147.687 us; speedup vs baseline: 9.6864x; 1.0462x over previous
//
#include <hip/hip_runtime.h>
#include <hip/hip_fp16.h>

// ---------------------------------------------------------------------------
// 2-layer GCN: out = GCNConv2( relu(GCNConv1(x)) )
// GCNConv(x,W,b): h = x@W ; out[d] = dinv[d]*( sum_{s->d} h[s]*dinv[s] + h[d]*dinv[d] ) + b
// dinv = rsqrt(in-degree + 1) (self-loops).
//
// Build = counting sort with exact bases (zero global atomics):
//  A1 hist_gemm: per-block LDS hist over 128-node buckets -> H[bucket][block];
//     payload/meta to sequential tmp. gemm1 (x@W1 -> f16, MFMA) fused in.
//  A2 scan_hist: exact (bucket,block) bases + totals T.
//  A3 place: tmp -> packed per-bucket arena.
//  B  cluster_csr: LDS-atomic scatter into padded per-node CSR + counts+dinv.
// agg1: 8 nodes/wave H8 gathers (1KB/instr), relu, f16 out.
// agg2_gemm: layer-2 linearity lets us aggregate h directly and apply W2
//   ONCE per dst in an MFMA epilogue (acc->LDS f16, @W2, +b2 -> d_out).
//   gemm2 kernel deleted.
// (History: LDS f32 atomics = 9x regression r10; degree-sort perm = net
// regression r11; H8 agg neutral r12 -> aggs are at random-gather ceiling.)
// ---------------------------------------------------------------------------

#define CAP   64      // per-node CSR slots (max in-degree ~40 at 12 sigma)
#define CAPB  3072    // arena slots per 128-node bucket (mean ~2046)
#define BKMAX 1024

typedef _Float16 f16x8 __attribute__((ext_vector_type(8)));
typedef float f32x4 __attribute__((ext_vector_type(4)));

struct alignas(16) H8 { __half2 a, b, c, d; };

// Detect whether edge_index was stored as int64 (all high words of values <N
// are zero) or int32 (odd words are random node ids, nonzero w.h.p.).
__global__ void detect_i64_kernel(const unsigned int* __restrict__ w, int ncheck,
                                  int* __restrict__ flag) {
  __shared__ int nz;
  if (threadIdx.x == 0) nz = 0;
  __syncthreads();
  for (int i = threadIdx.x; i < ncheck; i += blockDim.x) {
    if (w[2 * i + 1] != 0u) nz = 1;
  }
  __syncthreads();
  if (threadIdx.x == 0) flag[0] = (nz == 0) ? 1 : 0;
}

// A1 fused with GEMM1. Blocks [0,SB): 2048 edges each -> LDS hist, tmp
// streams, H row. Blocks [SB, SB+G1): g = x @ W1 (unscaled f16, MFMA).
__global__ __launch_bounds__(256) void hist_gemm_kernel(
    const int* __restrict__ edges, int E, const int* __restrict__ flag,
    int* __restrict__ Hh, int SB, int nbk,
    int* __restrict__ tmp_pk, int* __restrict__ tmp_mt,
    const float* __restrict__ A, const float* __restrict__ W,
    __half* __restrict__ g, int n) {
  __shared__ __align__(16) char smem[34816];  // union: {Af,Wf} | hist
  const int t = threadIdx.x;
  const int bid = (int)blockIdx.x;

  if (bid < SB) {
    int* hist = (int*)smem;  // [BKMAX]
    const int f = flag[0];
    const int blk0 = bid * 2048;

    for (int i = t; i < nbk; i += 256) hist[i] = 0;
    __syncthreads();

    if (blk0 + 2048 <= E) {  // full block: 8 edges/thread, vector loads
      int sv[8], dv[8];
      if (f) {  // int64 storage: value in low word of each qword
#pragma unroll
        for (int u = 0; u < 4; ++u) {
          const int eg = blk0 + (u * 256 + t) * 2;  // pair of edges
          const int4 a = *(const int4*)&edges[2 * (size_t)eg];
          const int4 b = *(const int4*)&edges[2 * ((size_t)E + eg)];
          sv[u * 2] = a.x; sv[u * 2 + 1] = a.z;
          dv[u * 2] = b.x; dv[u * 2 + 1] = b.z;
        }
      } else {
#pragma unroll
        for (int u = 0; u < 2; ++u) {
          const int eg = blk0 + (u * 256 + t) * 4;
          const int4 a = *(const int4*)&edges[eg];
          const int4 b = *(const int4*)&edges[(size_t)E + eg];
          sv[u * 4] = a.x; sv[u * 4 + 1] = a.y; sv[u * 4 + 2] = a.z; sv[u * 4 + 3] = a.w;
          dv[u * 4] = b.x; dv[u * 4 + 1] = b.y; dv[u * 4 + 2] = b.z; dv[u * 4 + 3] = b.w;
        }
      }
      int pk[8], mt[8];
#pragma unroll
      for (int i = 0; i < 8; ++i) {
        const int bk = dv[i] >> 7;
        const int rk = atomicAdd(&hist[bk], 1);
        pk[i] = ((dv[i] & 127) << 17) | sv[i];
        mt[i] = bk | (rk << 10);
      }
      if (f) {
#pragma unroll
        for (int u = 0; u < 4; ++u) {
          const int eg = blk0 + (u * 256 + t) * 2;
          *(int2*)&tmp_pk[eg] = make_int2(pk[u * 2], pk[u * 2 + 1]);
          *(int2*)&tmp_mt[eg] = make_int2(mt[u * 2], mt[u * 2 + 1]);
        }
      } else {
        *(int4*)&tmp_pk[blk0 + t * 4]        = make_int4(pk[0], pk[1], pk[2], pk[3]);
        *(int4*)&tmp_pk[blk0 + 1024 + t * 4] = make_int4(pk[4], pk[5], pk[6], pk[7]);
        *(int4*)&tmp_mt[blk0 + t * 4]        = make_int4(mt[0], mt[1], mt[2], mt[3]);
        *(int4*)&tmp_mt[blk0 + 1024 + t * 4] = make_int4(mt[4], mt[5], mt[6], mt[7]);
      }
    } else {  // tail block
      for (int e = blk0 + t; e < E; e += 256) {
        const int s = f ? edges[2 * (size_t)e] : edges[e];
        const int d = f ? edges[2 * ((size_t)E + e)] : edges[(size_t)E + e];
        const int bk = d >> 7;
        const int rk = atomicAdd(&hist[bk], 1);
        tmp_pk[e] = ((d & 127) << 17) | s;
        tmp_mt[e] = bk | (rk << 10);
      }
    }
    __syncthreads();
    for (int i = t; i < nbk; i += 256) Hh[(size_t)i * SB + bid] = hist[i];
    return;
  }

  // ---------------- GEMM1 path (MFMA f16, K=128) ----------------
  _Float16 (*Af)[136] = (_Float16(*)[136])smem;            // A[row][k], +8 pad
  _Float16 (*Wf)[136] = (_Float16(*)[136])(smem + 17408);  // Wt[col][k]
  const int row0 = (bid - SB) * 64;

  {  // stage A tile (64x128 f32 -> f16), coalesced
    const int r = t >> 2, k0 = (t & 3) << 5;
    const int gr = row0 + r;
    if (gr < n) {
#pragma unroll
      for (int q = 0; q < 4; ++q) {
        float4 a = *(const float4*)&A[(size_t)gr * 128 + k0 + q * 8];
        float4 b = *(const float4*)&A[(size_t)gr * 128 + k0 + q * 8 + 4];
        f16x8 v;
        v[0] = (_Float16)a.x; v[1] = (_Float16)a.y; v[2] = (_Float16)a.z; v[3] = (_Float16)a.w;
        v[4] = (_Float16)b.x; v[5] = (_Float16)b.y; v[6] = (_Float16)b.z; v[7] = (_Float16)b.w;
        *(f16x8*)&Af[r][k0 + q * 8] = v;
      }
    } else {
      f16x8 z = {0, 0, 0, 0, 0, 0, 0, 0};
#pragma unroll
      for (int q = 0; q < 4; ++q) *(f16x8*)&Af[r][k0 + q * 8] = z;
    }
  }
  {  // stage W transposed (Wt[col][k]), coalesced per k-row
    const int c = t & 63, kq = t >> 6;
#pragma unroll
    for (int i = 0; i < 32; ++i)
      Wf[c][kq * 32 + i] = (_Float16)W[(size_t)(kq * 32 + i) * 64 + c];
  }
  __syncthreads();

  const int wid = t >> 6, lane = t & 63;
  const int lr = lane & 15, kg = lane >> 4;
  f32x4 acc[4] = {{0, 0, 0, 0}, {0, 0, 0, 0}, {0, 0, 0, 0}, {0, 0, 0, 0}};
#pragma unroll
  for (int kc = 0; kc < 4; ++kc) {
    f16x8 av = *(const f16x8*)&Af[wid * 16 + lr][kc * 32 + kg * 8];
#pragma unroll
    for (int ct = 0; ct < 4; ++ct) {
      f16x8 bv = *(const f16x8*)&Wf[ct * 16 + lr][kc * 32 + kg * 8];
      acc[ct] = __builtin_amdgcn_mfma_f32_16x16x32_f16(av, bv, acc[ct], 0, 0, 0);
    }
  }
#pragma unroll
  for (int ct = 0; ct < 4; ++ct) {
#pragma unroll
    for (int rg = 0; rg < 4; ++rg) {
      const int r = row0 + wid * 16 + kg * 4 + rg;
      if (r < n) g[(size_t)r * 64 + ct * 16 + lr] = (__half)(float)acc[ct][rg];
    }
  }
}

// A2: per-bucket exclusive scan of H row (SB entries) + bucket total T.
__global__ __launch_bounds__(256) void scan_hist_kernel(
    int* __restrict__ Hh, int SB, int* __restrict__ T) {
  __shared__ int sm[256];
  __shared__ int carry;
  const int b = blockIdx.x;
  const int t = threadIdx.x;
  if (t == 0) carry = 0;
  __syncthreads();
  int* __restrict__ row = Hh + (size_t)b * SB;
  for (int base = 0; base < SB; base += 256) {
    const int i = base + t;
    const int v = (i < SB) ? row[i] : 0;
    sm[t] = v;
    __syncthreads();
    for (int off = 1; off < 256; off <<= 1) {
      int u = (t >= off) ? sm[t - off] : 0;
      __syncthreads();
      sm[t] += u;
      __syncthreads();
    }
    const int excl = sm[t] - v + carry;
    if (i < SB) row[i] = excl;
    __syncthreads();
    if (t == 0) carry += sm[255];
    __syncthreads();
  }
  if (t == 0) T[b] = carry;
}

// A3: stream tmp, place each edge at its exact arena slot. No atomics.
__global__ __launch_bounds__(256) void place_kernel(
    const int* __restrict__ tmp_pk, const int* __restrict__ tmp_mt,
    const int* __restrict__ Hh, int SB, int E, int* __restrict__ arena) {
  const int e0 = ((int)blockIdx.x * 256 + (int)threadIdx.x) * 4;
  if (e0 >= E) return;
  const int blk = e0 >> 11;  // originating A1 block (2048-edge chunks)
  if (e0 + 4 <= E) {
    const int4 pk = *(const int4*)&tmp_pk[e0];
    const int4 mt = *(const int4*)&tmp_mt[e0];
    const int b0 = mt.x & 1023, b1 = mt.y & 1023, b2 = mt.z & 1023, b3 = mt.w & 1023;
    const int p0 = Hh[(size_t)b0 * SB + blk] + (mt.x >> 10);
    const int p1 = Hh[(size_t)b1 * SB + blk] + (mt.y >> 10);
    const int p2 = Hh[(size_t)b2 * SB + blk] + (mt.z >> 10);
    const int p3 = Hh[(size_t)b3 * SB + blk] + (mt.w >> 10);
    if (p0 < CAPB) arena[(size_t)b0 * CAPB + p0] = pk.x;
    if (p1 < CAPB) arena[(size_t)b1 * CAPB + p1] = pk.y;
    if (p2 < CAPB) arena[(size_t)b2 * CAPB + p2] = pk.z;
    if (p3 < CAPB) arena[(size_t)b3 * CAPB + p3] = pk.w;
  } else {
    for (int e = e0; e < E; ++e) {
      const int mt = tmp_mt[e];
      const int bk = mt & 1023;
      const int p = Hh[(size_t)bk * SB + blk] + (mt >> 10);
      if (p < CAPB) arena[(size_t)bk * CAPB + p] = tmp_pk[e];
    }
  }
}

// Pass B: one block (512 thr) per 128-node bucket. LDS-atomic ranks ->
// padded per-node CSR; emits counts + dinv.
__global__ __launch_bounds__(512) void cluster_csr_kernel(
    const int* __restrict__ T, const int* __restrict__ arena,
    int n, int* __restrict__ counts, float* __restrict__ dinv,
    int* __restrict__ csrp) {
  __shared__ int lc[128];
  const int b = blockIdx.x;
  const int t = threadIdx.x;
  if (t < 128) lc[t] = 0;
  __syncthreads();
  int cnt = T[b];
  if (cnt > CAPB) cnt = CAPB;
  const int* __restrict__ seg = &arena[(size_t)b * CAPB];
  for (int j = t; j < cnt; j += 512) {
    const int p = seg[j];
    const int dl = p >> 17;
    const int s = p & 131071;
    const int r = atomicAdd(&lc[dl], 1);
    if (r < CAP) csrp[((size_t)(b << 7) + dl) * CAP + r] = s;
  }
  __syncthreads();
  const int d = (b << 7) + t;
  if (t < 128 && d < n) {
    counts[d] = lc[t];
    dinv[d] = rsqrtf((float)(lc[t] + 1));
  }
}

// agg1: 8 nodes per wave; 8-lane group per node, 16B H8 gathers; per-edge
// dinv[s] weight; epilogue relu -> f16 h.
__global__ __launch_bounds__(256) void agg1_kernel(
    const __half* __restrict__ hs, const int* __restrict__ counts,
    const int* __restrict__ csrp, const float* __restrict__ dinv,
    const float* __restrict__ bias, __half* __restrict__ out, int n) {
  const int wid = blockIdx.x * 4 + ((int)threadIdx.x >> 6);
  if (wid * 8 >= n) return;
  const int lane = (int)threadIdx.x & 63;
  const int og = lane >> 3;  // node slot 0..7
  const int gl = lane & 7;   // channel group: channels gl*8 .. gl*8+8
  const int d = wid * 8 + og;
  const bool active = d < n;
  const int dc = active ? d : n - 1;

  int len = counts[dc];
  if (len > CAP) len = CAP;
  if (!active) len = 0;
  const int* __restrict__ row = &csrp[(size_t)dc * CAP];
  const float dd = dinv[dc];

  H8 sv = *(const H8*)&hs[(size_t)dc * 64 + (gl << 3)];
  float acc[8];
  {
    float2 f0 = __half22float2(sv.a), f1 = __half22float2(sv.b);
    float2 f2 = __half22float2(sv.c), f3 = __half22float2(sv.d);
    acc[0] = dd * f0.x; acc[1] = dd * f0.y; acc[2] = dd * f1.x; acc[3] = dd * f1.y;
    acc[4] = dd * f2.x; acc[5] = dd * f2.y; acc[6] = dd * f3.x; acc[7] = dd * f3.y;
  }

  for (int j = 0; __any(j < len); j += 8) {
    int sidx[8];
    bool pr[8];
#pragma unroll
    for (int u = 0; u < 8; ++u) {
      pr[u] = (j + u) < len;
      sidx[u] = pr[u] ? row[j + u] : dc;
    }
    H8 v[8];
#pragma unroll
    for (int u = 0; u < 8; ++u) v[u] = *(const H8*)&hs[(size_t)sidx[u] * 64 + (gl << 3)];
#pragma unroll
    for (int u = 0; u < 8; ++u) {
      const float w = pr[u] ? dinv[sidx[u]] : 0.f;
      float2 g0 = __half22float2(v[u].a), g1 = __half22float2(v[u].b);
      float2 g2 = __half22float2(v[u].c), g3 = __half22float2(v[u].d);
      acc[0] = fmaf(w, g0.x, acc[0]); acc[1] = fmaf(w, g0.y, acc[1]);
      acc[2] = fmaf(w, g1.x, acc[2]); acc[3] = fmaf(w, g1.y, acc[3]);
      acc[4] = fmaf(w, g2.x, acc[4]); acc[5] = fmaf(w, g2.y, acc[5]);
      acc[6] = fmaf(w, g3.x, acc[6]); acc[7] = fmaf(w, g3.y, acc[7]);
    }
  }

  if (active) {
    const float4 b0 = *(const float4*)&bias[gl << 3];
    const float4 b1 = *(const float4*)&bias[(gl << 3) + 4];
    float o[8];
    o[0] = fmaf(acc[0], dd, b0.x); o[1] = fmaf(acc[1], dd, b0.y);
    o[2] = fmaf(acc[2], dd, b0.z); o[3] = fmaf(acc[3], dd, b0.w);
    o[4] = fmaf(acc[4], dd, b1.x); o[5] = fmaf(acc[5], dd, b1.y);
    o[6] = fmaf(acc[6], dd, b1.z); o[7] = fmaf(acc[7], dd, b1.w);
#pragma unroll
    for (int c = 0; c < 8; ++c) o[c] = fmaxf(o[c], 0.f);
    H8 hv;
    hv.a = __floats2half2_rn(o[0], o[1]); hv.b = __floats2half2_rn(o[2], o[3]);
    hv.c = __floats2half2_rn(o[4], o[5]); hv.d = __floats2half2_rn(o[6], o[7]);
    *(H8*)&out[(size_t)d * 64 + (gl << 3)] = hv;
  }
}

// agg2 + fused W2 (layer-2 linearity): gather h with dinv[s] weights,
// scale by dinv[d], stage 32-node acc block as f16 in LDS, apply W2 via
// MFMA (idle matrix pipe), add b2, write f32 out. gemm2 kernel eliminated.
__global__ __launch_bounds__(256) void agg2_gemm_kernel(
    const __half* __restrict__ hh, const int* __restrict__ counts,
    const int* __restrict__ csrp, const float* __restrict__ dinv,
    const float* __restrict__ W2, const float* __restrict__ b2,
    float* __restrict__ out, int n) {
  __shared__ __align__(16) _Float16 Wf[64][88];  // W2t[col][k], stride 88
  __shared__ __align__(16) _Float16 Ac[32][88];  // acc[node][k] f16
  const int t = threadIdx.x;

  {  // stage W2 transposed (before gather; consumed after the barrier)
    const int c = t & 63, kq = t >> 6;
#pragma unroll
    for (int i = 0; i < 16; ++i)
      Wf[c][kq * 16 + i] = (_Float16)W2[(size_t)(kq * 16 + i) * 64 + c];
  }

  const int wid = t >> 6;
  const int lane = t & 63;
  const int og = lane >> 3, gl = lane & 7;
  const int node0 = (int)blockIdx.x * 32;
  const int d = node0 + wid * 8 + og;
  const bool active = d < n;
  const int dc = active ? d : n - 1;

  int len = counts[dc];
  if (len > CAP) len = CAP;
  if (!active) len = 0;
  const int* __restrict__ row = &csrp[(size_t)dc * CAP];
  const float dd = dinv[dc];

  H8 sv = *(const H8*)&hh[(size_t)dc * 64 + (gl << 3)];
  float acc[8];
  {
    float2 f0 = __half22float2(sv.a), f1 = __half22float2(sv.b);
    float2 f2 = __half22float2(sv.c), f3 = __half22float2(sv.d);
    acc[0] = dd * f0.x; acc[1] = dd * f0.y; acc[2] = dd * f1.x; acc[3] = dd * f1.y;
    acc[4] = dd * f2.x; acc[5] = dd * f2.y; acc[6] = dd * f3.x; acc[7] = dd * f3.y;
  }

  for (int j = 0; __any(j < len); j += 8) {
    int sidx[8];
    bool pr[8];
#pragma unroll
    for (int u = 0; u < 8; ++u) {
      pr[u] = (j + u) < len;
      sidx[u] = pr[u] ? row[j + u] : dc;
    }
    H8 v[8];
#pragma unroll
    for (int u = 0; u < 8; ++u) v[u] = *(const H8*)&hh[(size_t)sidx[u] * 64 + (gl << 3)];
#pragma unroll
    for (int u = 0; u < 8; ++u) {
      const float w = pr[u] ? dinv[sidx[u]] : 0.f;
      float2 g0 = __half22float2(v[u].a), g1 = __half22float2(v[u].b);
      float2 g2 = __half22float2(v[u].c), g3 = __half22float2(v[u].d);
      acc[0] = fmaf(w, g0.x, acc[0]); acc[1] = fmaf(w, g0.y, acc[1]);
      acc[2] = fmaf(w, g1.x, acc[2]); acc[3] = fmaf(w, g1.y, acc[3]);
      acc[4] = fmaf(w, g2.x, acc[4]); acc[5] = fmaf(w, g2.y, acc[5]);
      acc[6] = fmaf(w, g3.x, acc[6]); acc[7] = fmaf(w, g3.y, acc[7]);
    }
  }

  {  // stage (dinv[d] * acc) as f16: Ac[local_node][k]
    const int lrow = wid * 8 + og;
    f16x8 av;
#pragma unroll
    for (int c = 0; c < 8; ++c) av[c] = (_Float16)(acc[c] * dd);
    *(f16x8*)&Ac[lrow][gl << 3] = av;
  }
  __syncthreads();

  // MFMA epilogue: out[32x64] = Ac[32x64] @ W2[64x64] + b2.
  // wave w: row-tile rt = w>>1 (16 rows), col-tiles ct0..ct0+1.
  const int lr = lane & 15, kg = lane >> 4;
  const int rt = wid >> 1;
  const int ct0 = (wid & 1) * 2;
#pragma unroll
  for (int cti = 0; cti < 2; ++cti) {
    const int ct = ct0 + cti;
    f32x4 c4 = {0, 0, 0, 0};
#pragma unroll
    for (int kc = 0; kc < 2; ++kc) {
      f16x8 a = *(const f16x8*)&Ac[rt * 16 + lr][kc * 32 + kg * 8];
      f16x8 b = *(const f16x8*)&Wf[ct * 16 + lr][kc * 32 + kg * 8];
      c4 = __builtin_amdgcn_mfma_f32_16x16x32_f16(a, b, c4, 0, 0, 0);
    }
    const float bb = b2[ct * 16 + lr];
#pragma unroll
    for (int rg = 0; rg < 4; ++rg) {
      const int r = node0 + rt * 16 + kg * 4 + rg;
      if (r < n) out[(size_t)r * 64 + ct * 16 + lr] = (float)c4[rg] + bb;
    }
  }
}

extern "C" void kernel_launch(void* const* d_in, const int* in_sizes, int n_in,
                              void* d_out, int out_size, void* d_ws, size_t ws_size,
                              hipStream_t stream) {
  const float* x  = (const float*)d_in[0];
  const int*   ei = (const int*)d_in[1];
  const float* W1 = (const float*)d_in[2];
  const float* b1 = (const float*)d_in[3];
  const float* W2 = (const float*)d_in[4];
  const float* b2 = (const float*)d_in[5];
  float* out = (float*)d_out;

  const int N = in_sizes[0] / 128;  // 100000
  const int E = in_sizes[1] / 2;    // 1600000
  const int NBK = (N + 127) >> 7;   // 782 buckets of 128 nodes
  const int SB = (E + 2047) / 2048; // 782 hist blocks (2048 edges each)
  const int G1 = (N + 63) / 64;     // gemm blocks

  char* ws = (char*)d_ws;
  size_t off = 0;
  auto take = [&](size_t bytes) -> void* {
    void* p = ws + off;
    off += (bytes + 255) & ~(size_t)255;
    return p;
  };
  int*    flag   = (int*)take(sizeof(int));
  int*    Hh     = (int*)take((size_t)NBK * SB * 4);    // 2.4 MB hist matrix
  int*    T      = (int*)take((size_t)NBK * 4);
  int*    counts = (int*)take((size_t)N * 4);
  float*  dinv   = (float*)take((size_t)N * 4);
  int*    tmp_pk = (int*)take((size_t)E * 4);           // 6.4 MB
  int*    tmp_mt = (int*)take((size_t)E * 4);           // 6.4 MB
  int*    arena  = (int*)take((size_t)NBK * CAPB * 4);  // 9.6 MB
  int*    csrp   = (int*)take((size_t)N * CAP * 4);     // 25.6 MB
  __half* hsf    = (__half*)take((size_t)N * 64 * 2);   // gemm1 out (f16)
  __half* hh     = (__half*)take((size_t)N * 64 * 2);   // post layer-1 h (f16)
  (void)ws_size; (void)n_in; (void)out_size;

  detect_i64_kernel<<<1, 256, 0, stream>>>((const unsigned int*)ei, 4096, flag);

  // A1: per-block hist + tmp streams || g = x@W1 (f16, MFMA).
  hist_gemm_kernel<<<SB + G1, 256, 0, stream>>>(
      ei, E, flag, Hh, SB, NBK, tmp_pk, tmp_mt, x, W1, hsf, N);

  // A2: exact per-(bucket,block) bases + bucket totals.
  scan_hist_kernel<<<NBK, 256, 0, stream>>>(Hh, SB, T);

  // A3: place edges at exact arena slots (atomic-free).
  place_kernel<<<((E + 3) / 4 + 255) / 256, 256, 0, stream>>>(
      tmp_pk, tmp_mt, Hh, SB, E, arena);

  // B: per-bucket LDS-atomic CSR + counts + dinv.
  cluster_csr_kernel<<<NBK, 512, 0, stream>>>(T, arena, N, counts, dinv, csrp);

  // h = relu(dinv[d]*(sum dinv[s]*g[s] + dinv[d]*g[d]) + b1)  -> f16
  agg1_kernel<<<(N + 31) / 32, 256, 0, stream>>>(
      hsf, counts, csrp, dinv, b1, hh, N);

  // out = (dinv[d]*(sum dinv[s]*h[s] + dinv[d]*h[d])) @ W2 + b2  (MFMA epi)
  agg2_gemm_kernel<<<(N + 31) / 32, 256, 0, stream>>>(
      hh, counts, csrp, dinv, W2, b2, out, N);
}